// Round 2
// baseline (719.034 us; speedup 1.0000x reference)
//
#include <hip/hip_runtime.h>

#define NLEVELS 16
#define HSIZE (1u << 19)
#define HMASK ((1u << 19) - 1u)
#define P2 73856093u
#define P3 19349663u

// clang-native 16B vector: __builtin_nontemporal_* accepts this (not HIP float4)
typedef float nf4 __attribute__((ext_vector_type(4)));

// res[L] = floor(16 * (2^(1/3))^L)
__constant__ int c_res[NLEVELS] = {16, 20, 25, 32, 40, 50, 64, 80,
                                   101, 128, 161, 203, 256, 322, 406, 512};

// ---------------------------------------------------------------------------
// Per-point trilinear hash encode. Inlined 4x per thread; compiler hoists the
// independent gathers -> up to 32 outstanding table loads per thread.
// ---------------------------------------------------------------------------
__device__ __forceinline__ void encode_one(
    float x, float y, float z, const float2* __restrict__ tab, float rm1,
    float& o0, float& o1)
{
    float px = (x + 1.0f) * 0.5f;
    float py = (y + 1.0f) * 0.5f;
    float pz = (z + 1.0f) * 0.5f;
    float sx = px * rm1, sy = py * rm1, sz = pz * rm1;
    float bx = floorf(sx), by = floorf(sy), bz = floorf(sz);
    float fx = sx - bx, fy = sy - by, fz = sz - bz;

    unsigned ix = (unsigned)(int)bx;
    unsigned iy = (unsigned)(int)by;
    unsigned iz = (unsigned)(int)bz;

    unsigned s00 = ix + iy * P2 + iz * P3;
    unsigned h000 = s00 & HMASK,             h100 = (s00 + 1u) & HMASK;
    unsigned h010 = (s00 + P2) & HMASK,      h110 = (s00 + P2 + 1u) & HMASK;
    unsigned h001 = (s00 + P3) & HMASK,      h101 = (s00 + P3 + 1u) & HMASK;
    unsigned h011 = (s00 + P2 + P3) & HMASK, h111 = (s00 + P2 + P3 + 1u) & HMASK;

    // pair order: (h, h+1) share a 64B line 7/8 of the time -> L1 partner hit
    float2 f000 = tab[h000]; float2 f100 = tab[h100];
    float2 f010 = tab[h010]; float2 f110 = tab[h110];
    float2 f001 = tab[h001]; float2 f101 = tab[h101];
    float2 f011 = tab[h011]; float2 f111 = tab[h111];

    float wx0 = 1.0f - fx, wy0 = 1.0f - fy, wz0 = 1.0f - fz;
    float a0 = 0.0f, a1 = 0.0f, w;
    w = wx0 * wy0 * wz0; a0 += w * f000.x; a1 += w * f000.y;
    w = wx0 * wy0 * fz;  a0 += w * f001.x; a1 += w * f001.y;
    w = wx0 * fy * wz0;  a0 += w * f010.x; a1 += w * f010.y;
    w = wx0 * fy * fz;   a0 += w * f011.x; a1 += w * f011.y;
    w = fx * wy0 * wz0;  a0 += w * f100.x; a1 += w * f100.y;
    w = fx * wy0 * fz;   a0 += w * f101.x; a1 += w * f101.y;
    w = fx * fy * wz0;   a0 += w * f110.x; a1 += w * f110.y;
    w = fx * fy * fz;    a0 += w * f111.x; a1 += w * f111.y;
    o0 = a0; o1 = a1;
}

// ---------------------------------------------------------------------------
// Kernel A: level-major compute, XCD affinity (xcd = blockIdx % 8 heuristic),
// FOUR consecutive points per thread:
//   - positions loaded as 3x nf4 nontemporal (read-once per phase; keep the
//     4 MiB level table resident in the XCD's L2)
//   - 32 independent gathers in flight per thread (latency amortization)
//   - output to tiled ws [chunk256][16][256]*float2 via 2x nt 16B stores
// ---------------------------------------------------------------------------
template <bool TO_WS>
__global__ __launch_bounds__(256) void hashgrid_kernel(
    const float* __restrict__ positions,  // [npoints, 3]
    const float* __restrict__ tables,     // [16, 2^19, 2]
    float2* __restrict__ dst,             // TO_WS: tiled ws; else out [npoints][16]
    int npoints)
{
    int nch = (npoints + 1023) >> 10;     // 1024 points per block
    int b = blockIdx.x;
    int L, chunk;
    if (TO_WS) {
        int xcd = b & 7;
        int j = b >> 3;                   // [0, 2*nch)
        L = xcd + ((j >= nch) ? 8 : 0);
        chunk = (j >= nch) ? (j - nch) : j;
    } else {
        L = b / nch;
        chunk = b - L * nch;
    }
    int t = threadIdx.x;
    int p0 = (chunk << 10) + (t << 2);
    if (p0 >= npoints) return;

    float rm1 = (float)(c_res[L] - 1);
    const float2* __restrict__ tab = (const float2*)tables + (size_t)L * HSIZE;

    float o0[4], o1[4];
    if (p0 + 3 < npoints) {
        const nf4* pos4 = (const nf4*)(positions + (size_t)chunk * 3072);
        nf4 q0 = __builtin_nontemporal_load(&pos4[3 * t + 0]); // x0 y0 z0 x1
        nf4 q1 = __builtin_nontemporal_load(&pos4[3 * t + 1]); // y1 z1 x2 y2
        nf4 q2 = __builtin_nontemporal_load(&pos4[3 * t + 2]); // z2 x3 y3 z3

        encode_one(q0[0], q0[1], q0[2], tab, rm1, o0[0], o1[0]);
        encode_one(q0[3], q1[0], q1[1], tab, rm1, o0[1], o1[1]);
        encode_one(q1[2], q1[3], q2[0], tab, rm1, o0[2], o1[2]);
        encode_one(q2[1], q2[2], q2[3], tab, rm1, o0[3], o1[3]);

        if (TO_WS) {
            // ws float2 index: ((p>>8)*16 + L)*256 + (p&255); 4 pts contiguous
            size_t tile = (size_t)((chunk << 2) + (t >> 6)) * NLEVELS + L;
            nf4* wp = (nf4*)dst + tile * 128 + (size_t)(t & 63) * 2;
            nf4 v0 = {o0[0], o1[0], o0[1], o1[1]};
            nf4 v1 = {o0[2], o1[2], o0[3], o1[3]};
            __builtin_nontemporal_store(v0, wp);
            __builtin_nontemporal_store(v1, wp + 1);
        } else {
#pragma unroll
            for (int k = 0; k < 4; ++k)
                dst[(size_t)(p0 + k) * NLEVELS + L] = make_float2(o0[k], o1[k]);
        }
    } else {
        // scalar tail (never taken at npoints = 2^20)
        for (int k = 0; k < 4 && p0 + k < npoints; ++k) {
            int p = p0 + k;
            encode_one(positions[3 * p], positions[3 * p + 1], positions[3 * p + 2],
                       tab, rm1, o0[k], o1[k]);
            if (TO_WS)
                dst[((size_t)(p >> 8) * NLEVELS + L) * 256 + (p & 255)] =
                    make_float2(o0[k], o1[k]);
            else
                dst[(size_t)p * NLEVELS + L] = make_float2(o0[k], o1[k]);
        }
    }
}

// ---------------------------------------------------------------------------
// Kernel B: tile transpose. ws tile c = [16][256] float2 (16 KB, contiguous)
//   -> out tile [256][16] float2 (contiguous). 16B on BOTH global sides,
// parity-interleaved LDS rows keep conflicts <=4-way. nt both streams.
// ---------------------------------------------------------------------------
__global__ __launch_bounds__(256) void transpose_kernel(
    const nf4* __restrict__ ws4,
    nf4* __restrict__ out4,
    int npoints)
{
    __shared__ float2 lds[256][NLEVELS + 1];
    int c = blockIdx.x;
    int t = threadIdx.x;
    size_t base = (size_t)c * 2048;   // 2048 x 16B per tile

#pragma unroll
    for (int k = 0; k < 8; ++k) {
        int i = (k << 8) + t;                 // 16B covers f2 {2i, 2i+1}
        nf4 v = __builtin_nontemporal_load(&ws4[base + i]);
        int L = i >> 7;                       // level
        int m = i & 127;                      // pts 2m, 2m+1
        lds[m][L]       = make_float2(v[0], v[1]);   // row(2m)   = m
        lds[m + 128][L] = make_float2(v[2], v[3]);   // row(2m+1) = m+128
    }
    __syncthreads();

#pragma unroll
    for (int k = 0; k < 8; ++k) {
        int i = (k << 8) + t;
        int pp = i >> 3;                      // point within tile
        int q = i & 7;                        // level pair
        int r = (pp >> 1) | ((pp & 1) << 7);  // physical row of point pp
        float2 a = lds[r][2 * q];
        float2 bb = lds[r][2 * q + 1];
        nf4 v = {a.x, a.y, bb.x, bb.y};
        __builtin_nontemporal_store(v, &out4[base + i]);
    }
}

extern "C" void kernel_launch(void* const* d_in, const int* in_sizes, int n_in,
                              void* d_out, int out_size, void* d_ws, size_t ws_size,
                              hipStream_t stream) {
    const float* positions = (const float*)d_in[0];
    const float* tables = (const float*)d_in[1];
    int npoints = in_sizes[0] / 3;                    // 1,048,576
    int nch = (npoints + 1023) >> 10;
    int blocks = NLEVELS * nch;

    size_t ws_needed = (size_t)NLEVELS * npoints * sizeof(float2);  // 128 MiB
    if (ws_size >= ws_needed && (npoints & 255) == 0) {
        float2* ws = (float2*)d_ws;
        hashgrid_kernel<true><<<blocks, 256, 0, stream>>>(positions, tables, ws, npoints);
        transpose_kernel<<<npoints / 256, 256, 0, stream>>>((const nf4*)ws,
                                                            (nf4*)d_out, npoints);
    } else {
        hashgrid_kernel<false><<<blocks, 256, 0, stream>>>(positions, tables,
                                                           (float2*)d_out, npoints);
    }
}

// Round 4
// 506.990 us; speedup vs baseline: 1.4182x; 1.4182x over previous
//
#include <hip/hip_runtime.h>

#define NLEVELS 16
#define HSIZE (1u << 19)
#define HMASK ((1u << 19) - 1u)
#define P2 73856093u
#define P3 19349663u

// clang-native 16B vector (accepted by __builtin_nontemporal_*, unlike HIP float4)
typedef float nf4 __attribute__((ext_vector_type(4)));

// res[L] = floor(16 * (2^(1/3))^L)
__constant__ int c_res[NLEVELS] = {16, 20, 25, 32, 40, 50, 64, 80,
                                   101, 128, 161, 203, 256, 322, 406, 512};

// ---------------------------------------------------------------------------
// Kernel A: level-major, XCD affinity (xcd = blockIdx % 8), ONE point/thread
// (r0 structure: wave count is the MLP source — r2 proved per-thread unroll
// serializes).  NEW: paired-corner gathers. Corners (h, h+1) are adjacent
// float2s in the table -> one 16B load covers both => 4 gathers/point not 8,
// halving the L1 address-pipe occupancy (the theorized bottleneck).
// Wrap case h==HMASK (p=2^-19) handled branchlessly via clamp+select with
// tab[0] preloaded (wave-uniform -> s_load).
// nt policy: positions/tables/ws all TEMPORAL (positions re-read 16x must stay
// in L3; ws re-read by kernel B must stay in L3). Only final out is nt.
// ---------------------------------------------------------------------------
template <bool TO_WS>
__global__ __launch_bounds__(256) void hashgrid_kernel(
    const float* __restrict__ positions,  // [npoints, 3]
    const float* __restrict__ tables,     // [16, 2^19, 2]
    float2* __restrict__ dst,             // TO_WS: tiled ws; else out [npoints][16]
    int npoints)
{
    int nch = (npoints + 255) >> 8;       // 256-point chunks
    int b = blockIdx.x;
    int L, chunk;
    if (TO_WS) {
        int xcd = b & 7;
        int j = b >> 3;                   // [0, 2*nch)
        L = xcd + ((j >= nch) ? 8 : 0);
        chunk = (j >= nch) ? (j - nch) : j;
    } else {
        L = b / nch;
        chunk = b - L * nch;
    }
    int p = (chunk << 8) + threadIdx.x;
    if (p >= npoints) return;

    float px = (positions[3 * p + 0] + 1.0f) * 0.5f;
    float py = (positions[3 * p + 1] + 1.0f) * 0.5f;
    float pz = (positions[3 * p + 2] + 1.0f) * 0.5f;

    float rm1 = (float)(c_res[L] - 1);
    float sx = px * rm1, sy = py * rm1, sz = pz * rm1;
    float bx = floorf(sx), by = floorf(sy), bz = floorf(sz);
    float fx = sx - bx, fy = sy - by, fz = sz - bz;

    unsigned ix = (unsigned)(int)bx;
    unsigned iy = (unsigned)(int)by;
    unsigned iz = (unsigned)(int)bz;

    unsigned s00 = ix + iy * P2 + iz * P3;
    // pair k covers corners (x=0, x=1) at (dy,dz) = (0,0),(1,0),(0,1),(1,1)
    unsigned hl0 = s00 & HMASK;
    unsigned hl1 = (s00 + P2) & HMASK;
    unsigned hl2 = (s00 + P3) & HMASK;
    unsigned hl3 = (s00 + P2 + P3) & HMASK;

    const float* tabf = tables + (size_t)L * (2u * HSIZE);
    float2 t0 = ((const float2*)tabf)[0];         // wave-uniform wrap partner

    unsigned w0 = (hl0 == HMASK) ? 1u : 0u;
    unsigned w1 = (hl1 == HMASK) ? 1u : 0u;
    unsigned w2 = (hl2 == HMASK) ? 1u : 0u;
    unsigned w3 = (hl3 == HMASK) ? 1u : 0u;

    // 16B paired loads: entries {h-w, h-w+1}. All 4 independent -> in flight.
    nf4 g0 = *(const nf4*)(tabf + 2u * (hl0 - w0));
    nf4 g1 = *(const nf4*)(tabf + 2u * (hl1 - w1));
    nf4 g2 = *(const nf4*)(tabf + 2u * (hl2 - w2));
    nf4 g3 = *(const nf4*)(tabf + 2u * (hl3 - w3));

    // lo corner = entry h, hi corner = entry (h+1)&HMASK
    float l0x = w0 ? g0.z : g0.x, l0y = w0 ? g0.w : g0.y;
    float h0x = w0 ? t0.x : g0.z, h0y = w0 ? t0.y : g0.w;
    float l1x = w1 ? g1.z : g1.x, l1y = w1 ? g1.w : g1.y;
    float h1x = w1 ? t0.x : g1.z, h1y = w1 ? t0.y : g1.w;
    float l2x = w2 ? g2.z : g2.x, l2y = w2 ? g2.w : g2.y;
    float h2x = w2 ? t0.x : g2.z, h2y = w2 ? t0.y : g2.w;
    float l3x = w3 ? g3.z : g3.x, l3y = w3 ? g3.w : g3.y;
    float h3x = w3 ? t0.x : g3.z, h3y = w3 ? t0.y : g3.w;

    float wx0 = 1.0f - fx, wy0 = 1.0f - fy, wz0 = 1.0f - fz;
    float c0 = wy0 * wz0;   // (dy,dz)=(0,0)
    float c1 = fy * wz0;    // (1,0)
    float c2 = wy0 * fz;    // (0,1)
    float c3 = fy * fz;     // (1,1)

    float o0 = c0 * (wx0 * l0x + fx * h0x)
             + c1 * (wx0 * l1x + fx * h1x)
             + c2 * (wx0 * l2x + fx * h2x)
             + c3 * (wx0 * l3x + fx * h3x);
    float o1 = c0 * (wx0 * l0y + fx * h0y)
             + c1 * (wx0 * l1y + fx * h1y)
             + c2 * (wx0 * l2y + fx * h2y)
             + c3 * (wx0 * l3y + fx * h3y);

    if (TO_WS) {
        // tiled ws: f2 index = ((p>>8)*16 + L)*256 + (p&255); wave writes
        // 512 contiguous bytes (8B/lane, coalesced). Temporal: L3 keeps it
        // for kernel B.
        dst[((size_t)chunk * NLEVELS + L) * 256 + threadIdx.x] = make_float2(o0, o1);
    } else {
        dst[(size_t)p * NLEVELS + L] = make_float2(o0, o1);
    }
}

// ---------------------------------------------------------------------------
// Kernel B: tile transpose. ws tile c = [16][256] float2 (16 KB contiguous)
//   -> out tile [256][16] float2 (contiguous). 16B on BOTH global sides.
// Plain loads (ws is L3-resident after temporal stores in A); nt out stores
// (never re-read).
// ---------------------------------------------------------------------------
__global__ __launch_bounds__(256) void transpose_kernel(
    const nf4* __restrict__ ws4,
    nf4* __restrict__ out4,
    int npoints)
{
    __shared__ float2 lds[256][NLEVELS + 1];
    int c = blockIdx.x;
    int t = threadIdx.x;
    size_t base = (size_t)c * 2048;   // 2048 x 16B per tile

#pragma unroll
    for (int k = 0; k < 8; ++k) {
        int i = (k << 8) + t;                 // 16B covers f2 {2i, 2i+1}
        nf4 v = ws4[base + i];
        int L = i >> 7;                       // level
        int m = i & 127;                      // pts 2m, 2m+1
        lds[m][L]       = make_float2(v.x, v.y);   // row(2m)   = m
        lds[m + 128][L] = make_float2(v.z, v.w);   // row(2m+1) = m+128
    }
    __syncthreads();

#pragma unroll
    for (int k = 0; k < 8; ++k) {
        int i = (k << 8) + t;
        int pp = i >> 3;                      // point within tile
        int q = i & 7;                        // level pair
        int r = (pp >> 1) | ((pp & 1) << 7);  // physical row of point pp
        float2 a = lds[r][2 * q];
        float2 bb = lds[r][2 * q + 1];
        nf4 v = {a.x, a.y, bb.x, bb.y};
        __builtin_nontemporal_store(v, &out4[base + i]);
    }
}

extern "C" void kernel_launch(void* const* d_in, const int* in_sizes, int n_in,
                              void* d_out, int out_size, void* d_ws, size_t ws_size,
                              hipStream_t stream) {
    const float* positions = (const float*)d_in[0];
    const float* tables = (const float*)d_in[1];
    int npoints = in_sizes[0] / 3;                    // 1,048,576
    int nch = (npoints + 255) >> 8;
    int blocks = NLEVELS * nch;                       // 65,536

    size_t ws_needed = (size_t)NLEVELS * npoints * sizeof(float2);  // 128 MiB
    if (ws_size >= ws_needed && (npoints & 255) == 0) {
        float2* ws = (float2*)d_ws;
        hashgrid_kernel<true><<<blocks, 256, 0, stream>>>(positions, tables, ws, npoints);
        transpose_kernel<<<npoints / 256, 256, 0, stream>>>((const nf4*)ws,
                                                            (nf4*)d_out, npoints);
    } else {
        hashgrid_kernel<false><<<blocks, 256, 0, stream>>>(positions, tables,
                                                           (float2*)d_out, npoints);
    }
}